// Round 1
// baseline (250.984 us; speedup 1.0000x reference)
//
#include <hip/hip_runtime.h>

typedef float  f32x4 __attribute__((ext_vector_type(4)));
typedef float  f32x2 __attribute__((ext_vector_type(2)));
typedef short  short8v __attribute__((ext_vector_type(8)));

static __device__ __forceinline__ unsigned short f2bf(float f) {
  union { float f; unsigned u; } v; v.f = f;
  unsigned r = v.u + 0x7FFFu + ((v.u >> 16) & 1u);   // RNE
  return (unsigned short)(r >> 16);
}
static __device__ __forceinline__ float bf2f(unsigned short h) {
  union { unsigned u; float f; } v; v.u = ((unsigned)h) << 16;
  return v.f;
}
static __device__ __forceinline__ f32x4 mfma16(short8v a, short8v b, f32x4 c) {
  return __builtin_amdgcn_mfma_f32_16x16x32_bf16(a, b, c, 0, 0, 0);
}

// ---- adj pooling: out[j,k] = sum_{a,b in 0..3} in[(2j+a)%nin][(2k+b)%nin]
__global__ __launch_bounds__(256) void pool_adj_kernel(const float* __restrict__ in,
                                                       float* __restrict__ out,
                                                       int n, int nin) {
  int k = blockIdx.x * 32 + (threadIdx.x & 31);
  int j = blockIdx.y * 8 + (threadIdx.x >> 5);
  if (k >= n || j >= n) return;
  int c0 = 2 * k, r0 = 2 * j;
  float s = 0.f;
  #pragma unroll
  for (int a = 0; a < 4; ++a) {
    const float* row = in + (size_t)((r0 + a) & (nin - 1)) * nin;
    if (c0 + 3 < nin) {
      f32x2 u = *(const f32x2*)(row + c0);
      f32x2 w = *(const f32x2*)(row + c0 + 2);
      s += u[0] + u[1] + w[0] + w[1];
    } else {
      #pragma unroll
      for (int b = 0; b < 4; ++b) s += row[(c0 + b) & (nin - 1)];
    }
  }
  out[(size_t)j * n + k] = s;
}

// ---- d[j] = rsqrt(max(rowsum - diag + 1, 1))
__global__ __launch_bounds__(256) void rowsum_kernel(const float* __restrict__ adj,
                                                     float* __restrict__ dv, int n) {
  int j = blockIdx.x;
  const float* row = adj + (size_t)j * n;
  float s = 0.f;
  for (int k = threadIdx.x; k < n; k += 256) s += row[k];
  #pragma unroll
  for (int o = 32; o > 0; o >>= 1) s += __shfl_xor(s, o);
  __shared__ float red[4];
  if ((threadIdx.x & 63) == 0) red[threadIdx.x >> 6] = s;
  __syncthreads();
  if (threadIdx.x == 0) {
    float t = red[0] + red[1] + red[2] + red[3] - row[j] + 1.f;
    dv[j] = rsqrtf(fmaxf(t, 1.f));
  }
}

// ---- out[j,:] = sum of rows {2j..2j+3 mod nin} of in [nin,128]
__global__ __launch_bounds__(256) void pool_rows_kernel(const float* __restrict__ in,
                                                        float* __restrict__ out,
                                                        int nout, int nin) {
  int idx = blockIdx.x * 256 + threadIdx.x;
  if (idx >= nout * 128) return;
  int j = idx >> 7, d = idx & 127;
  int r0 = 2 * j;
  float s = 0.f;
  #pragma unroll
  for (int a = 0; a < 4; ++a) s += in[(size_t)((r0 + a) & (nin - 1)) * 128 + d];
  out[idx] = s;
}

// ---- optionally scale rows, emit f32 copy, bf16 hi/lo, and transposed bf16 hi
__global__ __launch_bounds__(256) void split_transpose_kernel(const float* __restrict__ X,
                                                              const float* __restrict__ scale,
                                                              float* __restrict__ Yf,
                                                              unsigned short* __restrict__ Oh,
                                                              unsigned short* __restrict__ Ol,
                                                              unsigned short* __restrict__ OT,
                                                              int M) {
  __shared__ unsigned short t[32][33];
  int i0 = blockIdx.x * 32, d0 = blockIdx.y * 32;
  int tx = threadIdx.x & 31, ty = threadIdx.x >> 5;
  #pragma unroll
  for (int rr = 0; rr < 4; ++rr) {
    int i = i0 + ty + rr * 8;
    int d = d0 + tx;
    float v = X[(size_t)i * 128 + d];
    if (scale) v *= scale[i];
    unsigned short hi = f2bf(v);
    if (Yf) Yf[(size_t)i * 128 + d] = v;
    if (Oh) {
      Oh[(size_t)i * 128 + d] = hi;
      Ol[(size_t)i * 128 + d] = f2bf(v - bf2f(hi));
    }
    t[ty + rr * 8][tx] = hi;
  }
  __syncthreads();
  #pragma unroll
  for (int rr = 0; rr < 4; ++rr) {
    int d = d0 + ty + rr * 8;
    int i = i0 + tx;
    OT[(size_t)d * M + i] = t[tx][ty + rr * 8];
  }
}

// ---- O[M,128] = X[M,128] @ W[128,128] (f32); optional bf16 hi/lo split output
__global__ __launch_bounds__(128) void gemm128_kernel(const float* __restrict__ X,
                                                      const float* __restrict__ W,
                                                      float* __restrict__ O,
                                                      unsigned short* __restrict__ Oh,
                                                      unsigned short* __restrict__ Ol) {
  __shared__ float xs[16][128];
  int r0 = blockIdx.x * 16;
  int d = threadIdx.x;
  #pragma unroll
  for (int i = 0; i < 16; ++i) xs[i][d] = X[(size_t)(r0 + i) * 128 + d];
  __syncthreads();
  float acc[16];
  #pragma unroll
  for (int i = 0; i < 16; ++i) acc[i] = 0.f;
  for (int e = 0; e < 128; e += 4) {
    float w0 = W[(e + 0) * 128 + d];
    float w1 = W[(e + 1) * 128 + d];
    float w2 = W[(e + 2) * 128 + d];
    float w3 = W[(e + 3) * 128 + d];
    #pragma unroll
    for (int i = 0; i < 16; ++i) {
      f32x4 xv = *(const f32x4*)&xs[i][e];
      float a = acc[i];
      a = fmaf(xv[0], w0, a);
      a = fmaf(xv[1], w1, a);
      a = fmaf(xv[2], w2, a);
      a = fmaf(xv[3], w3, a);
      acc[i] = a;
    }
  }
  #pragma unroll
  for (int i = 0; i < 16; ++i) {
    size_t o = (size_t)(r0 + i) * 128 + d;
    if (Oh) {
      unsigned short hi = f2bf(acc[i]);
      Oh[o] = hi;
      Ol[o] = f2bf(acc[i] - bf2f(hi));
    } else {
      O[o] = acc[i];
    }
  }
}

// ---- C[M,128] = A_f32[M,K] @ B[K,128], B given transposed bf16 BT[128,K]
__global__ __launch_bounds__(64) void mfma_gemm_kernel(const float* __restrict__ A,
                                                       const unsigned short* __restrict__ BT,
                                                       float* __restrict__ C, int K) {
  int jt = blockIdx.x, nt = blockIdx.y;
  int lane = threadIdx.x;
  int q = lane & 15, g = lane >> 4;
  const float* arow = A + (size_t)(jt * 16 + q) * K;
  const unsigned short* brow = BT + (size_t)(nt * 16 + q) * K;
  f32x4 acc = {0.f, 0.f, 0.f, 0.f};
  for (int k0 = 0; k0 < K; k0 += 32) {
    int ka = k0 + g * 8;
    f32x4 a0 = *(const f32x4*)(arow + ka);
    f32x4 a1 = *(const f32x4*)(arow + ka + 4);
    short8v af;
    af[0] = (short)f2bf(a0[0]); af[1] = (short)f2bf(a0[1]);
    af[2] = (short)f2bf(a0[2]); af[3] = (short)f2bf(a0[3]);
    af[4] = (short)f2bf(a1[0]); af[5] = (short)f2bf(a1[1]);
    af[6] = (short)f2bf(a1[2]); af[7] = (short)f2bf(a1[3]);
    short8v bf = *(const short8v*)(brow + ka);
    acc = mfma16(af, bf, acc);
  }
  #pragma unroll
  for (int r = 0; r < 4; ++r)
    C[(size_t)(jt * 16 + g * 4 + r) * 128 + nt * 16 + q] = acc[r];
}

// ---- split-K flash attention partials.
// Grid 2048: block (jt,kc) handles q-rows jt*16..+15 over k-range kc*256..+255.
// S computed transposed (A=K tile, B=Q^T) so each lane owns q = lane&15.
// Masked scores (k in {2j..2j+3 mod 4096}) are set to exactly 0 (per reference).
__global__ __launch_bounds__(64) void flash_kernel(const unsigned short* __restrict__ Qh,
                                                   const unsigned short* __restrict__ Ql,
                                                   const unsigned short* __restrict__ Kh,
                                                   const unsigned short* __restrict__ Kl,
                                                   const unsigned short* __restrict__ VT,
                                                   float* __restrict__ pacc,
                                                   float* __restrict__ pm,
                                                   float* __restrict__ pl) {
  int bid = blockIdx.x;
  int jt = bid >> 4, kc = bid & 15;
  int lane = threadIdx.x;
  int q = lane & 15, g = lane >> 4;
  int j = jt * 16 + q;
  int kbase = kc * 256;
  int twoj = 2 * j;
  __shared__ unsigned short P[16][32];

  short8v qh[4], ql[4];
  #pragma unroll
  for (int c = 0; c < 4; ++c) {
    qh[c] = *(const short8v*)&Qh[(size_t)j * 128 + c * 32 + g * 8];
    ql[c] = *(const short8v*)&Ql[(size_t)j * 128 + c * 32 + g * 8];
  }
  float m = -1e30f, l = 0.f;
  f32x4 acc[8];
  #pragma unroll
  for (int t = 0; t < 8; ++t) acc[t] = (f32x4){0.f, 0.f, 0.f, 0.f};

  for (int step = 0; step < 8; ++step) {
    int kt = kbase + step * 32;
    const unsigned short* ka_h = Kh + (size_t)(kt + q) * 128;
    const unsigned short* ka_l = Kl + (size_t)(kt + q) * 128;
    const unsigned short* kb_h = Kh + (size_t)(kt + 16 + q) * 128;
    const unsigned short* kb_l = Kl + (size_t)(kt + 16 + q) * 128;
    f32x4 s0 = {0.f, 0.f, 0.f, 0.f}, s1 = {0.f, 0.f, 0.f, 0.f};
    #pragma unroll
    for (int c = 0; c < 4; ++c) {
      int off = c * 32 + g * 8;
      short8v ah = *(const short8v*)(ka_h + off);
      short8v al = *(const short8v*)(ka_l + off);
      short8v bh = *(const short8v*)(kb_h + off);
      short8v bl = *(const short8v*)(kb_l + off);
      s0 = mfma16(ah, qh[c], s0);       // bf16x3: hh + h*lo + lo*h
      s1 = mfma16(bh, qh[c], s1);
      s0 = mfma16(ah, ql[c], s0);
      s1 = mfma16(bh, ql[c], s1);
      s0 = mfma16(al, qh[c], s0);
      s1 = mfma16(bl, qh[c], s1);
    }
    float sv[8];
    #pragma unroll
    for (int r = 0; r < 4; ++r) {
      int k0 = kt + g * 4 + r;          // D row = k-within-tile = 4g+r
      float v0 = s0[r];
      if (((k0 - twoj) & 4095) < 4) v0 = 0.f;
      sv[r] = v0;
      int k1 = k0 + 16;
      float v1 = s1[r];
      if (((k1 - twoj) & 4095) < 4) v1 = 0.f;
      sv[4 + r] = v1;
    }
    float cmx = sv[0];
    #pragma unroll
    for (int r = 1; r < 8; ++r) cmx = fmaxf(cmx, sv[r]);
    cmx = fmaxf(cmx, __shfl_xor(cmx, 16));
    cmx = fmaxf(cmx, __shfl_xor(cmx, 32));
    float mnew = fmaxf(m, cmx);
    float scl = __expf(m - mnew);       // step 0: exp(-huge)=0, acc already 0
    float ps = 0.f;
    unsigned short pb[8];
    #pragma unroll
    for (int r = 0; r < 8; ++r) {
      float pv = __expf(sv[r] - mnew);
      ps += pv;
      pb[r] = f2bf(pv);
    }
    ps += __shfl_xor(ps, 16);
    ps += __shfl_xor(ps, 32);
    l = l * scl + ps;
    m = mnew;
    // rescale acc: acc row q' = 4g+r needs scale owned by lanes with lane&15==q'
    float sc0 = __shfl(scl, 4 * g + 0);
    float sc1 = __shfl(scl, 4 * g + 1);
    float sc2 = __shfl(scl, 4 * g + 2);
    float sc3 = __shfl(scl, 4 * g + 3);
    #pragma unroll
    for (int t = 0; t < 8; ++t) {
      acc[t][0] *= sc0; acc[t][1] *= sc1; acc[t][2] *= sc2; acc[t][3] *= sc3;
    }
    // write P[q][k_local]: tile a k_local=4g+r, tile b 16+4g+r (packed pairs)
    *(unsigned*)&P[q][4 * g]          = (unsigned)pb[0] | ((unsigned)pb[1] << 16);
    *(unsigned*)&P[q][4 * g + 2]      = (unsigned)pb[2] | ((unsigned)pb[3] << 16);
    *(unsigned*)&P[q][16 + 4 * g]     = (unsigned)pb[4] | ((unsigned)pb[5] << 16);
    *(unsigned*)&P[q][16 + 4 * g + 2] = (unsigned)pb[6] | ((unsigned)pb[7] << 16);
    __syncthreads();
    short8v pa = *(const short8v*)&P[q][8 * g];   // A-frag: row q, k=8g+e
    const unsigned short* vb = VT + kt + g * 8;
    #pragma unroll
    for (int t = 0; t < 8; ++t) {
      short8v bv = *(const short8v*)(vb + (size_t)(t * 16 + q) * 4096);
      acc[t] = mfma16(pa, bv, acc[t]);
    }
    __syncthreads();
  }
  #pragma unroll
  for (int t = 0; t < 8; ++t) {
    #pragma unroll
    for (int r = 0; r < 4; ++r)
      pacc[((size_t)(jt * 16 + g * 4 + r) * 16 + kc) * 128 + t * 16 + q] = acc[t][r];
  }
  if (g == 0) {
    pm[(size_t)j * 16 + kc] = m;
    pl[(size_t)j * 16 + kc] = l;
  }
}

// ---- merge 16 split-K partials per q-row; x1 = alpha@x + x1b
__global__ __launch_bounds__(128) void combine_kernel(const float* __restrict__ pacc,
                                                      const float* __restrict__ pm,
                                                      const float* __restrict__ pl,
                                                      const float* __restrict__ x1b,
                                                      float* __restrict__ x1) {
  int j = blockIdx.x, d = threadIdx.x;
  float M = -1e30f;
  #pragma unroll
  for (int c = 0; c < 16; ++c) M = fmaxf(M, pm[(size_t)j * 16 + c]);
  float L = 0.f, o = 0.f;
  for (int c = 0; c < 16; ++c) {
    float w = __expf(pm[(size_t)j * 16 + c] - M);
    L += pl[(size_t)j * 16 + c] * w;
    o += w * pacc[((size_t)j * 16 + c) * 128 + d];
  }
  x1[(size_t)j * 128 + d] = o / L + x1b[(size_t)j * 128 + d];
}

// ---- H[j,:] = (relu?)( d[j]*(G[j,:] + (1-diag)*y[j,:]) + bias )
__global__ __launch_bounds__(256) void gcn_epi_kernel(const float* __restrict__ G,
                                                      const float* __restrict__ y,
                                                      const float* __restrict__ dv,
                                                      const float* __restrict__ adj,
                                                      const float* __restrict__ bias,
                                                      float* __restrict__ H,
                                                      int n, int do_relu) {
  int idx = blockIdx.x * 256 + threadIdx.x;
  if (idx >= n * 128) return;
  int j = idx >> 7, d = idx & 127;
  float diag = adj[(size_t)j * n + j];
  float v = dv[j] * (G[idx] + (1.f - diag) * y[idx]) + bias[d];
  H[idx] = do_relu ? fmaxf(v, 0.f) : v;
}

__global__ __launch_bounds__(128) void colsum_kernel(const float* __restrict__ H,
                                                     float* __restrict__ partial, int rpb) {
  int d = threadIdx.x, b = blockIdx.x;
  float s = 0.f;
  for (int i = 0; i < rpb; ++i) s += H[(size_t)(b * rpb + i) * 128 + d];
  partial[(size_t)b * 128 + d] = s;
}

__global__ __launch_bounds__(128) void final_kernel(const float* __restrict__ partial, int nb,
                                                    const float* __restrict__ b2,
                                                    const float* __restrict__ Wlin,
                                                    const float* __restrict__ blin,
                                                    float* __restrict__ out) {
  int d = threadIdx.x;
  float cs = 0.f;
  for (int b = 0; b < nb; ++b) cs += partial[(size_t)b * 128 + d];
  // rows >=1024 of h2 are exactly b2 each (zero x2, identity-normalized diag)
  float mean = (cs + 1024.f * b2[d]) * (1.f / 2048.f);
  __shared__ float r0[128], r1[128];
  r0[d] = mean * Wlin[d];
  r1[d] = mean * Wlin[128 + d];
  __syncthreads();
  for (int s = 64; s > 0; s >>= 1) {
    if (d < s) { r0[d] += r0[d + s]; r1[d] += r1[d + s]; }
    __syncthreads();
  }
  if (d == 0) {
    float z0 = fmaxf(r0[0] + blin[0], 0.f);
    float z1 = fmaxf(r1[0] + blin[1], 0.f);
    float mz = fmaxf(z0, z1);
    float lse = mz + logf(__expf(z0 - mz) + __expf(z1 - mz));
    out[0] = z0 - lse;
    out[1] = z1 - lse;
  }
}

extern "C" void kernel_launch(void* const* d_in, const int* in_sizes, int n_in,
                              void* d_out, int out_size, void* d_ws, size_t ws_size,
                              hipStream_t stream) {
  const float* x      = (const float*)d_in[0];
  const float* eidx   = (const float*)d_in[1];
  const float* newadj = eidx + (size_t)4096 * 4096;  // edge_index[1]
  const float* ca1    = (const float*)d_in[3];
  const float* W1     = (const float*)d_in[4];
  const float* b1     = (const float*)d_in[5];
  const float* W2     = (const float*)d_in[6];
  const float* b2     = (const float*)d_in[7];
  const float* Wlin   = (const float*)d_in[8];
  const float* blin   = (const float*)d_in[9];
  float* out = (float*)d_out;

  if (ws_size < 41u * 1024u * 1024u) return;  // need ~40.2 MB

  char* p = (char*)d_ws;
  auto alloc = [&](size_t bytes) -> char* {
    char* r = p; p += (bytes + 255) & ~(size_t)255; return r;
  };
  // persistent buffers
  float* adj1 = (float*)alloc((size_t)2048 * 2048 * 4);
  float* d1   = (float*)alloc(2048 * 4);
  float* x1b  = (float*)alloc((size_t)2048 * 128 * 4);
  unsigned short* QhB = (unsigned short*)alloc((size_t)2048 * 128 * 2);
  unsigned short* QlB = (unsigned short*)alloc((size_t)2048 * 128 * 2);
  unsigned short* KhB = (unsigned short*)alloc((size_t)4096 * 128 * 2);
  unsigned short* KlB = (unsigned short*)alloc((size_t)4096 * 128 * 2);
  unsigned short* VTB = (unsigned short*)alloc((size_t)4096 * 128 * 2);
  float* pmB  = (float*)alloc((size_t)2048 * 16 * 4);
  float* plB  = (float*)alloc((size_t)2048 * 16 * 4);
  float* x1   = (float*)alloc((size_t)2048 * 128 * 4);
  float* d2   = (float*)alloc(1024 * 4);
  // overlap region: pacc (16.78MB) lives here during attention; all post-combine
  // buffers are sub-allocated in the same region (pacc is dead by then).
  char* region = p;
  float* pacc = (float*)region;  // 2048*16*128*4
  char* q2 = region;
  auto alloc2 = [&](size_t bytes) -> char* {
    char* r = q2; q2 += (bytes + 255) & ~(size_t)255; return r;
  };
  float* xw   = (float*)alloc2((size_t)2048 * 128 * 4);
  float* yB   = (float*)alloc2((size_t)2048 * 128 * 4);
  unsigned short* yT  = (unsigned short*)alloc2((size_t)2048 * 128 * 2);
  float* G    = (float*)alloc2((size_t)2048 * 128 * 4);
  float* h    = (float*)alloc2((size_t)2048 * 128 * 4);
  float* x2   = (float*)alloc2((size_t)1024 * 128 * 4);
  float* adj2 = (float*)alloc2((size_t)1024 * 1024 * 4);
  float* out2 = (float*)alloc2((size_t)1024 * 128 * 4);
  float* y2   = (float*)alloc2((size_t)1024 * 128 * 4);
  unsigned short* y2T = (unsigned short*)alloc2((size_t)1024 * 128 * 2);
  float* G2   = (float*)alloc2((size_t)1024 * 128 * 4);
  float* h2   = (float*)alloc2((size_t)1024 * 128 * 4);
  float* part = (float*)alloc2((size_t)8 * 128 * 4);

  // 1. adj1 = pooled newadj
  pool_adj_kernel<<<dim3(2048 / 32, 2048 / 8), 256, 0, stream>>>(newadj, adj1, 2048, 4096);
  // 2. d1
  rowsum_kernel<<<2048, 256, 0, stream>>>(adj1, d1, 2048);
  // 3. x1b
  pool_rows_kernel<<<(2048 * 128) / 256, 256, 0, stream>>>(x, x1b, 2048, 4096);
  // 4. K hi/lo + V^T from x
  split_transpose_kernel<<<dim3(4096 / 32, 4), 256, 0, stream>>>(x, nullptr, nullptr, KhB, KlB, VTB, 4096);
  // 5. Q = x1b @ ca1, split to hi/lo
  gemm128_kernel<<<2048 / 16, 128, 0, stream>>>(x1b, ca1, nullptr, QhB, QlB);
  // 6. flash attention partials (bf16x3 QK^T, masked-to-zero scores)
  flash_kernel<<<2048, 64, 0, stream>>>(QhB, QlB, KhB, KlB, VTB, pacc, pmB, plB);
  // 7. combine -> x1
  combine_kernel<<<2048, 128, 0, stream>>>(pacc, pmB, plB, x1b, x1);
  // 8. xw = x1 @ W1
  gemm128_kernel<<<2048 / 16, 128, 0, stream>>>(x1, W1, xw, nullptr, nullptr);
  // 9. y = d1 .* xw ; yT bf16
  split_transpose_kernel<<<dim3(2048 / 32, 4), 256, 0, stream>>>(xw, d1, yB, nullptr, nullptr, yT, 2048);
  // 10. G = adj1 @ y (bf16 MFMA)
  mfma_gemm_kernel<<<dim3(2048 / 16, 8), 64, 0, stream>>>(adj1, yT, G, 2048);
  // 11. h = relu(d1*(G + (1-diag)*y) + b1)
  gcn_epi_kernel<<<(2048 * 128) / 256, 256, 0, stream>>>(G, yB, d1, adj1, b1, h, 2048, 1);
  // 12. x2 = row-pool(h)
  pool_rows_kernel<<<(1024 * 128) / 256, 256, 0, stream>>>(h, x2, 1024, 2048);
  // 13. adj2 = pooled adj1
  pool_adj_kernel<<<dim3(1024 / 32, 1024 / 8), 256, 0, stream>>>(adj1, adj2, 1024, 2048);
  // 14. d2
  rowsum_kernel<<<1024, 256, 0, stream>>>(adj2, d2, 1024);
  // 15. out2 = x2 @ W2
  gemm128_kernel<<<1024 / 16, 128, 0, stream>>>(x2, W2, out2, nullptr, nullptr);
  // 16. y2 = d2 .* out2 ; y2T
  split_transpose_kernel<<<dim3(1024 / 32, 4), 256, 0, stream>>>(out2, d2, y2, nullptr, nullptr, y2T, 1024);
  // 17. G2 = adj2 @ y2
  mfma_gemm_kernel<<<dim3(1024 / 16, 8), 64, 0, stream>>>(adj2, y2T, G2, 1024);
  // 18. h2 (no relu)
  gcn_epi_kernel<<<(1024 * 128) / 256, 256, 0, stream>>>(G2, y2, d2, adj2, b2, h2, 1024, 0);
  // 19. column partial sums of h2
  colsum_kernel<<<8, 128, 0, stream>>>(h2, part, 128);
  // 20. mean + linear + relu + log_softmax
  final_kernel<<<1, 128, 0, stream>>>(part, 8, b2, Wlin, blin, out);
}

// Round 2
// 227.078 us; speedup vs baseline: 1.1053x; 1.1053x over previous
//
#include <hip/hip_runtime.h>

typedef float  f32x4 __attribute__((ext_vector_type(4)));
typedef float  f32x2 __attribute__((ext_vector_type(2)));
typedef short  short8v __attribute__((ext_vector_type(8)));

static __device__ __forceinline__ unsigned short f2bf(float f) {
  union { float f; unsigned u; } v; v.f = f;
  unsigned r = v.u + 0x7FFFu + ((v.u >> 16) & 1u);   // RNE
  return (unsigned short)(r >> 16);
}
static __device__ __forceinline__ float bf2f(unsigned short h) {
  union { unsigned u; float f; } v; v.u = ((unsigned)h) << 16;
  return v.f;
}
static __device__ __forceinline__ f32x4 mfma16(short8v a, short8v b, f32x4 c) {
  return __builtin_amdgcn_mfma_f32_16x16x32_bf16(a, b, c, 0, 0, 0);
}

// ---- adj pooling: out[j,k] = sum_{a,b in 0..3} in[(2j+a)%nin][(2k+b)%nin]
//      also emits bf16 copy for MFMA A-operand
__global__ __launch_bounds__(256) void pool_adj_kernel(const float* __restrict__ in,
                                                       float* __restrict__ out,
                                                       unsigned short* __restrict__ outh,
                                                       int n, int nin) {
  int k = blockIdx.x * 32 + (threadIdx.x & 31);
  int j = blockIdx.y * 8 + (threadIdx.x >> 5);
  if (k >= n || j >= n) return;
  int c0 = 2 * k, r0 = 2 * j;
  float s = 0.f;
  #pragma unroll
  for (int a = 0; a < 4; ++a) {
    const float* row = in + (size_t)((r0 + a) & (nin - 1)) * nin;
    if (c0 + 3 < nin) {
      f32x2 u = *(const f32x2*)(row + c0);
      f32x2 w = *(const f32x2*)(row + c0 + 2);
      s += u[0] + u[1] + w[0] + w[1];
    } else {
      #pragma unroll
      for (int b = 0; b < 4; ++b) s += row[(c0 + b) & (nin - 1)];
    }
  }
  out[(size_t)j * n + k] = s;
  outh[(size_t)j * n + k] = f2bf(s);
}

// ---- d[j] = rsqrt(max(rowsum - diag + 1, 1))
__global__ __launch_bounds__(256) void rowsum_kernel(const float* __restrict__ adj,
                                                     float* __restrict__ dv, int n) {
  int j = blockIdx.x;
  const float* row = adj + (size_t)j * n;
  float s = 0.f;
  for (int k = threadIdx.x; k < n; k += 256) s += row[k];
  #pragma unroll
  for (int o = 32; o > 0; o >>= 1) s += __shfl_xor(s, o);
  __shared__ float red[4];
  if ((threadIdx.x & 63) == 0) red[threadIdx.x >> 6] = s;
  __syncthreads();
  if (threadIdx.x == 0) {
    float t = red[0] + red[1] + red[2] + red[3] - row[j] + 1.f;
    dv[j] = rsqrtf(fmaxf(t, 1.f));
  }
}

// ---- out[j,:] = sum of rows {2j..2j+3 mod nin} of in [nin,128]
__global__ __launch_bounds__(256) void pool_rows_kernel(const float* __restrict__ in,
                                                        float* __restrict__ out,
                                                        int nout, int nin) {
  int idx = blockIdx.x * 256 + threadIdx.x;
  if (idx >= nout * 128) return;
  int j = idx >> 7, d = idx & 127;
  int r0 = 2 * j;
  float s = 0.f;
  #pragma unroll
  for (int a = 0; a < 4; ++a) s += in[(size_t)((r0 + a) & (nin - 1)) * 128 + d];
  out[idx] = s;
}

// ---- emit bf16 hi/lo of X and transposed bf16 hi (for K and V^T)
__global__ __launch_bounds__(256) void split_transpose_kernel(const float* __restrict__ X,
                                                              unsigned short* __restrict__ Oh,
                                                              unsigned short* __restrict__ Ol,
                                                              unsigned short* __restrict__ OT,
                                                              int M) {
  __shared__ unsigned short t[32][33];
  int i0 = blockIdx.x * 32, d0 = blockIdx.y * 32;
  int tx = threadIdx.x & 31, ty = threadIdx.x >> 5;
  #pragma unroll
  for (int rr = 0; rr < 4; ++rr) {
    int i = i0 + ty + rr * 8;
    int d = d0 + tx;
    float v = X[(size_t)i * 128 + d];
    unsigned short hi = f2bf(v);
    Oh[(size_t)i * 128 + d] = hi;
    Ol[(size_t)i * 128 + d] = f2bf(v - bf2f(hi));
    t[ty + rr * 8][tx] = hi;
  }
  __syncthreads();
  #pragma unroll
  for (int rr = 0; rr < 4; ++rr) {
    int d = d0 + ty + rr * 8;
    int i = i0 + tx;
    OT[(size_t)d * M + i] = t[tx][ty + rr * 8];
  }
}

// ---- Q = X[M,128] @ W[128,128], split to bf16 hi/lo
__global__ __launch_bounds__(128) void gemm_q_kernel(const float* __restrict__ X,
                                                     const float* __restrict__ W,
                                                     unsigned short* __restrict__ Oh,
                                                     unsigned short* __restrict__ Ol) {
  __shared__ float xs[16][128];
  int r0 = blockIdx.x * 16;
  int d = threadIdx.x;
  #pragma unroll
  for (int i = 0; i < 16; ++i) xs[i][d] = X[(size_t)(r0 + i) * 128 + d];
  __syncthreads();
  float acc[16];
  #pragma unroll
  for (int i = 0; i < 16; ++i) acc[i] = 0.f;
  for (int e = 0; e < 128; e += 4) {
    float w0 = W[(e + 0) * 128 + d];
    float w1 = W[(e + 1) * 128 + d];
    float w2 = W[(e + 2) * 128 + d];
    float w3 = W[(e + 3) * 128 + d];
    #pragma unroll
    for (int i = 0; i < 16; ++i) {
      f32x4 xv = *(const f32x4*)&xs[i][e];
      float a = acc[i];
      a = fmaf(xv[0], w0, a);
      a = fmaf(xv[1], w1, a);
      a = fmaf(xv[2], w2, a);
      a = fmaf(xv[3], w3, a);
      acc[i] = a;
    }
  }
  #pragma unroll
  for (int i = 0; i < 16; ++i) {
    size_t o = (size_t)(r0 + i) * 128 + d;
    unsigned short hi = f2bf(acc[i]);
    Oh[o] = hi;
    Ol[o] = f2bf(acc[i] - bf2f(hi));
  }
}

// ---- Y = dv .* (X[M,128] @ W[128,128]); writes f32 Y and transposed bf16 YT
__global__ __launch_bounds__(128) void gemm_scale_kernel(const float* __restrict__ X,
                                                         const float* __restrict__ W,
                                                         const float* __restrict__ dv,
                                                         float* __restrict__ Yf,
                                                         unsigned short* __restrict__ YT,
                                                         int M) {
  __shared__ float xs[16][128];
  int r0 = blockIdx.x * 16;
  int d = threadIdx.x;
  #pragma unroll
  for (int i = 0; i < 16; ++i) xs[i][d] = X[(size_t)(r0 + i) * 128 + d];
  __syncthreads();
  float acc[16];
  #pragma unroll
  for (int i = 0; i < 16; ++i) acc[i] = 0.f;
  for (int e = 0; e < 128; e += 4) {
    float w0 = W[(e + 0) * 128 + d];
    float w1 = W[(e + 1) * 128 + d];
    float w2 = W[(e + 2) * 128 + d];
    float w3 = W[(e + 3) * 128 + d];
    #pragma unroll
    for (int i = 0; i < 16; ++i) {
      f32x4 xv = *(const f32x4*)&xs[i][e];
      float a = acc[i];
      a = fmaf(xv[0], w0, a);
      a = fmaf(xv[1], w1, a);
      a = fmaf(xv[2], w2, a);
      a = fmaf(xv[3], w3, a);
      acc[i] = a;
    }
  }
  short8v t0, t1;
  #pragma unroll
  for (int i = 0; i < 16; ++i) {
    float v = acc[i] * dv[r0 + i];
    Yf[(size_t)(r0 + i) * 128 + d] = v;
    if (i < 8) t0[i] = (short)f2bf(v); else t1[i - 8] = (short)f2bf(v);
  }
  *(short8v*)&YT[(size_t)d * M + r0] = t0;
  *(short8v*)&YT[(size_t)d * M + r0 + 8] = t1;
}

// ---- C_ks[M,128] partial = A_bf16[M, K-half] @ B, B transposed bf16 BT[128,K]
__global__ __launch_bounds__(64) void mfma_gemm_kernel(const unsigned short* __restrict__ A,
                                                       const unsigned short* __restrict__ BT,
                                                       float* __restrict__ C, int K, int M) {
  int jt = blockIdx.x, nt = blockIdx.y, ks = blockIdx.z;
  int lane = threadIdx.x;
  int q = lane & 15, g = lane >> 4;
  const unsigned short* arow = A + (size_t)(jt * 16 + q) * K;
  const unsigned short* brow = BT + (size_t)(nt * 16 + q) * K;
  int kbeg = ks * (K >> 1), kend = kbeg + (K >> 1);
  f32x4 acc = {0.f, 0.f, 0.f, 0.f};
  for (int k0 = kbeg; k0 < kend; k0 += 32) {
    int ka = k0 + g * 8;
    short8v af = *(const short8v*)(arow + ka);
    short8v bf = *(const short8v*)(brow + ka);
    acc = mfma16(af, bf, acc);
  }
  float* Cp = C + (size_t)ks * M * 128;
  #pragma unroll
  for (int r = 0; r < 4; ++r)
    Cp[(size_t)(jt * 16 + g * 4 + r) * 128 + nt * 16 + q] = acc[r];
}

// ---- split-K flash attention partials (bf16x3 QK^T, masked-to-zero scores).
// Block (jt,kc): q-rows jt*16..+15 over k-range kc*256..+255, 1 wave.
// S computed transposed (A=K tile, B=Q^T) so lane owns q = lane&15.
__global__ __launch_bounds__(64) void flash_kernel(const unsigned short* __restrict__ Qh,
                                                   const unsigned short* __restrict__ Ql,
                                                   const unsigned short* __restrict__ Kh,
                                                   const unsigned short* __restrict__ Kl,
                                                   const unsigned short* __restrict__ VT,
                                                   unsigned short* __restrict__ pacc,
                                                   float* __restrict__ pm,
                                                   float* __restrict__ pl) {
  int bid = blockIdx.x;
  int jt = bid >> 4, kc = bid & 15;
  int lane = threadIdx.x;
  int q = lane & 15, g = lane >> 4;
  int j = jt * 16 + q;
  int kbase = kc * 256;
  int twoj = 2 * j;
  __shared__ unsigned short P[16][32];

  short8v qh[4], ql[4];
  #pragma unroll
  for (int c = 0; c < 4; ++c) {
    qh[c] = *(const short8v*)&Qh[(size_t)j * 128 + c * 32 + g * 8];
    ql[c] = *(const short8v*)&Ql[(size_t)j * 128 + c * 32 + g * 8];
  }
  float m = -1e30f, l = 0.f;
  f32x4 acc[8];
  #pragma unroll
  for (int t = 0; t < 8; ++t) acc[t] = (f32x4){0.f, 0.f, 0.f, 0.f};

  for (int step = 0; step < 8; ++step) {
    int kt = kbase + step * 32;
    const unsigned short* ka_h = Kh + (size_t)(kt + q) * 128;
    const unsigned short* ka_l = Kl + (size_t)(kt + q) * 128;
    const unsigned short* kb_h = ka_h + 16 * 128;
    const unsigned short* kb_l = ka_l + 16 * 128;
    f32x4 z = {0.f, 0.f, 0.f, 0.f};
    f32x4 hh0 = z, hl0 = z, lh0 = z, hh1 = z, hl1 = z, lh1 = z;
    __builtin_amdgcn_s_setprio(1);
    #pragma unroll
    for (int c = 0; c < 4; ++c) {
      int off = c * 32 + g * 8;
      short8v ah = *(const short8v*)(ka_h + off);
      short8v al = *(const short8v*)(ka_l + off);
      short8v bh = *(const short8v*)(kb_h + off);
      short8v bl = *(const short8v*)(kb_l + off);
      hh0 = mfma16(ah, qh[c], hh0);   // 6 independent 4-deep chains
      hh1 = mfma16(bh, qh[c], hh1);
      hl0 = mfma16(ah, ql[c], hl0);
      hl1 = mfma16(bh, ql[c], hl1);
      lh0 = mfma16(al, qh[c], lh0);
      lh1 = mfma16(bl, qh[c], lh1);
    }
    __builtin_amdgcn_s_setprio(0);
    // prefetch V fragments now: consumed only after softmax, hides L2 latency
    short8v vfrag[8];
    const unsigned short* vb = VT + kt + g * 8;
    #pragma unroll
    for (int t = 0; t < 8; ++t)
      vfrag[t] = *(const short8v*)(vb + (size_t)(t * 16 + q) * 4096);

    f32x4 s0 = hh0 + hl0 + lh0;
    f32x4 s1 = hh1 + hl1 + lh1;
    float sv[8];
    #pragma unroll
    for (int r = 0; r < 4; ++r) {
      int k0 = kt + g * 4 + r;          // D row = k-within-tile = 4g+r
      float v0 = s0[r];
      if (((k0 - twoj) & 4095) < 4) v0 = 0.f;
      sv[r] = v0;
      int k1 = k0 + 16;
      float v1 = s1[r];
      if (((k1 - twoj) & 4095) < 4) v1 = 0.f;
      sv[4 + r] = v1;
    }
    float cmx = sv[0];
    #pragma unroll
    for (int r = 1; r < 8; ++r) cmx = fmaxf(cmx, sv[r]);
    cmx = fmaxf(cmx, __shfl_xor(cmx, 16));
    cmx = fmaxf(cmx, __shfl_xor(cmx, 32));
    float mnew = fmaxf(m, cmx);
    float ps = 0.f;
    unsigned short pb[8];
    #pragma unroll
    for (int r = 0; r < 8; ++r) {
      float pv = __expf(sv[r] - mnew);
      ps += pv;
      pb[r] = f2bf(pv);
    }
    ps += __shfl_xor(ps, 16);
    ps += __shfl_xor(ps, 32);
    if (__any(cmx > m)) {               // defer-rescale: skip when max didn't grow
      float scl = __expf(m - mnew);
      l *= scl;
      float sc0 = __shfl(scl, 4 * g + 0);
      float sc1 = __shfl(scl, 4 * g + 1);
      float sc2 = __shfl(scl, 4 * g + 2);
      float sc3 = __shfl(scl, 4 * g + 3);
      #pragma unroll
      for (int t = 0; t < 8; ++t) {
        acc[t][0] *= sc0; acc[t][1] *= sc1; acc[t][2] *= sc2; acc[t][3] *= sc3;
      }
    }
    m = mnew;
    l += ps;
    // write P[q][k_local]: tile a k_local=4g+r, tile b 16+4g+r (packed pairs)
    *(unsigned*)&P[q][4 * g]          = (unsigned)pb[0] | ((unsigned)pb[1] << 16);
    *(unsigned*)&P[q][4 * g + 2]      = (unsigned)pb[2] | ((unsigned)pb[3] << 16);
    *(unsigned*)&P[q][16 + 4 * g]     = (unsigned)pb[4] | ((unsigned)pb[5] << 16);
    *(unsigned*)&P[q][16 + 4 * g + 2] = (unsigned)pb[6] | ((unsigned)pb[7] << 16);
    __syncthreads();
    short8v pa = *(const short8v*)&P[q][8 * g];   // A-frag: row q, k=8g+e
    __builtin_amdgcn_s_setprio(1);
    #pragma unroll
    for (int t = 0; t < 8; ++t) acc[t] = mfma16(pa, vfrag[t], acc[t]);
    __builtin_amdgcn_s_setprio(0);
    __syncthreads();
  }
  #pragma unroll
  for (int t = 0; t < 8; ++t) {
    #pragma unroll
    for (int r = 0; r < 4; ++r)
      pacc[((size_t)(jt * 16 + g * 4 + r) * 16 + kc) * 128 + t * 16 + q] = f2bf(acc[t][r]);
  }
  if (g == 0) {
    pm[(size_t)j * 16 + kc] = m;
    pl[(size_t)j * 16 + kc] = l;
  }
}

// ---- merge 16 split-K partials per q-row; x1 = alpha@x + x1b
__global__ __launch_bounds__(128) void combine_kernel(const unsigned short* __restrict__ pacc,
                                                      const float* __restrict__ pm,
                                                      const float* __restrict__ pl,
                                                      const float* __restrict__ x1b,
                                                      float* __restrict__ x1) {
  int j = blockIdx.x, d = threadIdx.x;
  float M = -1e30f;
  #pragma unroll
  for (int c = 0; c < 16; ++c) M = fmaxf(M, pm[(size_t)j * 16 + c]);
  float L = 0.f, o = 0.f;
  for (int c = 0; c < 16; ++c) {
    float w = __expf(pm[(size_t)j * 16 + c] - M);
    L += pl[(size_t)j * 16 + c] * w;
    o += w * bf2f(pacc[((size_t)j * 16 + c) * 128 + d]);
  }
  x1[(size_t)j * 128 + d] = o / L + x1b[(size_t)j * 128 + d];
}

// ---- H[j,:] = (relu?)( d[j]*(Ga+Gb + (1-diag)*y) + bias )
__global__ __launch_bounds__(256) void gcn_epi_kernel(const float* __restrict__ G,
                                                      const float* __restrict__ y,
                                                      const float* __restrict__ dv,
                                                      const float* __restrict__ adj,
                                                      const float* __restrict__ bias,
                                                      float* __restrict__ H,
                                                      int n, int do_relu) {
  int idx = blockIdx.x * 256 + threadIdx.x;
  if (idx >= n * 128) return;
  int j = idx >> 7, d = idx & 127;
  float diag = adj[(size_t)j * n + j];
  float gs = G[idx] + G[(size_t)n * 128 + idx];
  float v = dv[j] * (gs + (1.f - diag) * y[idx]) + bias[d];
  H[idx] = do_relu ? fmaxf(v, 0.f) : v;
}

__global__ __launch_bounds__(128) void colsum_kernel(const float* __restrict__ H,
                                                     float* __restrict__ partial, int rpb) {
  int d = threadIdx.x, b = blockIdx.x;
  float s = 0.f;
  for (int i = 0; i < rpb; ++i) s += H[(size_t)(b * rpb + i) * 128 + d];
  partial[(size_t)b * 128 + d] = s;
}

__global__ __launch_bounds__(128) void final_kernel(const float* __restrict__ partial, int nb,
                                                    const float* __restrict__ b2,
                                                    const float* __restrict__ Wlin,
                                                    const float* __restrict__ blin,
                                                    float* __restrict__ out) {
  int d = threadIdx.x;
  float cs = 0.f;
  for (int b = 0; b < nb; ++b) cs += partial[(size_t)b * 128 + d];
  // rows >=1024 of h2 are exactly b2 each (zero x2, identity-normalized diag)
  float mean = (cs + 1024.f * b2[d]) * (1.f / 2048.f);
  __shared__ float r0[128], r1[128];
  r0[d] = mean * Wlin[d];
  r1[d] = mean * Wlin[128 + d];
  __syncthreads();
  for (int s = 64; s > 0; s >>= 1) {
    if (d < s) { r0[d] += r0[d + s]; r1[d] += r1[d + s]; }
    __syncthreads();
  }
  if (d == 0) {
    float z0 = fmaxf(r0[0] + blin[0], 0.f);
    float z1 = fmaxf(r1[0] + blin[1], 0.f);
    float mz = fmaxf(z0, z1);
    float lse = mz + logf(__expf(z0 - mz) + __expf(z1 - mz));
    out[0] = z0 - lse;
    out[1] = z1 - lse;
  }
}

extern "C" void kernel_launch(void* const* d_in, const int* in_sizes, int n_in,
                              void* d_out, int out_size, void* d_ws, size_t ws_size,
                              hipStream_t stream) {
  const float* x      = (const float*)d_in[0];
  const float* eidx   = (const float*)d_in[1];
  const float* newadj = eidx + (size_t)4096 * 4096;  // edge_index[1]
  const float* ca1    = (const float*)d_in[3];
  const float* W1     = (const float*)d_in[4];
  const float* b1     = (const float*)d_in[5];
  const float* W2     = (const float*)d_in[6];
  const float* b2     = (const float*)d_in[7];
  const float* Wlin   = (const float*)d_in[8];
  const float* blin   = (const float*)d_in[9];
  float* out = (float*)d_out;

  if (ws_size < 46u * 1024u * 1024u) return;

  char* p = (char*)d_ws;
  auto alloc = [&](size_t bytes) -> char* {
    char* r = p; p += (bytes + 255) & ~(size_t)255; return r;
  };
  // persistent buffers
  float* adj1 = (float*)alloc((size_t)2048 * 2048 * 4);
  unsigned short* adj1h = (unsigned short*)alloc((size_t)2048 * 2048 * 2);
  float* d1   = (float*)alloc(2048 * 4);
  float* x1b  = (float*)alloc((size_t)2048 * 128 * 4);
  unsigned short* QhB = (unsigned short*)alloc((size_t)2048 * 128 * 2);
  unsigned short* QlB = (unsigned short*)alloc((size_t)2048 * 128 * 2);
  unsigned short* KhB = (unsigned short*)alloc((size_t)4096 * 128 * 2);
  unsigned short* KlB = (unsigned short*)alloc((size_t)4096 * 128 * 2);
  unsigned short* VTB = (unsigned short*)alloc((size_t)4096 * 128 * 2);
  float* pmB  = (float*)alloc((size_t)2048 * 16 * 4);
  float* plB  = (float*)alloc((size_t)2048 * 16 * 4);
  float* x1   = (float*)alloc((size_t)2048 * 128 * 4);
  float* d2   = (float*)alloc(1024 * 4);
  // overlap region: pacc (8.4MB bf16) dead after combine; level-1/2 buffers reuse it
  char* region = p;
  unsigned short* pacc = (unsigned short*)region;  // 2048*16*128*2
  char* q2 = region;
  auto alloc2 = [&](size_t bytes) -> char* {
    char* r = q2; q2 += (bytes + 255) & ~(size_t)255; return r;
  };
  float* yB   = (float*)alloc2((size_t)2048 * 128 * 4);
  unsigned short* yT  = (unsigned short*)alloc2((size_t)2048 * 128 * 2);
  float* G    = (float*)alloc2((size_t)2 * 2048 * 128 * 4);   // 2 K-split partials
  float* h    = (float*)alloc2((size_t)2048 * 128 * 4);
  float* x2   = (float*)alloc2((size_t)1024 * 128 * 4);
  float* adj2 = (float*)alloc2((size_t)1024 * 1024 * 4);
  unsigned short* adj2h = (unsigned short*)alloc2((size_t)1024 * 1024 * 2);
  float* y2B  = (float*)alloc2((size_t)1024 * 128 * 4);
  unsigned short* y2T = (unsigned short*)alloc2((size_t)1024 * 128 * 2);
  float* G2   = (float*)alloc2((size_t)2 * 1024 * 128 * 4);
  float* h2   = (float*)alloc2((size_t)1024 * 128 * 4);
  float* part = (float*)alloc2((size_t)8 * 128 * 4);

  // 1. adj1 (+bf16) = pooled newadj
  pool_adj_kernel<<<dim3(2048 / 32, 2048 / 8), 256, 0, stream>>>(newadj, adj1, adj1h, 2048, 4096);
  // 2. d1
  rowsum_kernel<<<2048, 256, 0, stream>>>(adj1, d1, 2048);
  // 3. x1b
  pool_rows_kernel<<<(2048 * 128) / 256, 256, 0, stream>>>(x, x1b, 2048, 4096);
  // 4. K hi/lo + V^T from x
  split_transpose_kernel<<<dim3(4096 / 32, 4), 256, 0, stream>>>(x, KhB, KlB, VTB, 4096);
  // 5. Q = x1b @ ca1, split hi/lo
  gemm_q_kernel<<<2048 / 16, 128, 0, stream>>>(x1b, ca1, QhB, QlB);
  // 6. flash attention partials
  flash_kernel<<<2048, 64, 0, stream>>>(QhB, QlB, KhB, KlB, VTB, pacc, pmB, plB);
  // 7. combine -> x1
  combine_kernel<<<2048, 128, 0, stream>>>(pacc, pmB, plB, x1b, x1);
  // 8. y = d1 .* (x1 @ W1); yT bf16 transposed
  gemm_scale_kernel<<<2048 / 16, 128, 0, stream>>>(x1, W1, d1, yB, yT, 2048);
  // 9. G (2 partials) = adj1h @ y
  mfma_gemm_kernel<<<dim3(2048 / 16, 8, 2), 64, 0, stream>>>(adj1h, yT, G, 2048, 2048);
  // 10. h = relu(d1*(G + (1-diag)*y) + b1)
  gcn_epi_kernel<<<(2048 * 128) / 256, 256, 0, stream>>>(G, yB, d1, adj1, b1, h, 2048, 1);
  // 11. x2 = row-pool(h)
  pool_rows_kernel<<<(1024 * 128) / 256, 256, 0, stream>>>(h, x2, 1024, 2048);
  // 12. adj2 (+bf16) = pooled adj1
  pool_adj_kernel<<<dim3(1024 / 32, 1024 / 8), 256, 0, stream>>>(adj1, adj2, adj2h, 1024, 2048);
  // 13. d2
  rowsum_kernel<<<1024, 256, 0, stream>>>(adj2, d2, 1024);
  // 14. y2 = d2 .* (x2 @ W2); y2T bf16 transposed
  gemm_scale_kernel<<<1024 / 16, 128, 0, stream>>>(x2, W2, d2, y2B, y2T, 1024);
  // 15. G2 (2 partials) = adj2h @ y2
  mfma_gemm_kernel<<<dim3(1024 / 16, 8, 2), 64, 0, stream>>>(adj2h, y2T, G2, 1024, 1024);
  // 16. h2 (no relu)
  gcn_epi_kernel<<<(1024 * 128) / 256, 256, 0, stream>>>(G2, y2B, d2, adj2, b2, h2, 1024, 0);
  // 17. column partial sums of h2
  colsum_kernel<<<8, 128, 0, stream>>>(h2, part, 128);
  // 18. mean + linear + relu + log_softmax
  final_kernel<<<1, 128, 0, stream>>>(part, 8, b2, Wlin, blin, out);
}